// Round 1
// 790.484 us; speedup vs baseline: 1.0060x; 1.0060x over previous
//
#include <hip/hip_runtime.h>
#include <stdint.h>

// ---------- types ----------
typedef __attribute__((ext_vector_type(8)))  __bf16 bf16x8;   // MFMA A/B frag (4 VGPRs)
typedef __attribute__((ext_vector_type(16))) float  f32x16;   // 32x32 MFMA C/D frag
typedef unsigned short u16;
typedef __attribute__((ext_vector_type(8))) unsigned short u16x8;

#define GLOBAL_AS __attribute__((address_space(1)))
#define LDS_AS    __attribute__((address_space(3)))

__device__ __forceinline__ void load_lds16(const void* g, void* l) {
    __builtin_amdgcn_global_load_lds((const GLOBAL_AS void*)g, (LDS_AS void*)l, 16, 0, 0);
}

__device__ __forceinline__ u16 f2bf(float f) {
    union { float f; uint32_t u; } v; v.f = f;
    uint32_t r = v.u + 0x7FFFu + ((v.u >> 16) & 1u);   // RNE
    return (u16)(r >> 16);
}
__device__ __forceinline__ float b2f(u16 b) {
    union { uint32_t u; float f; } v; v.u = ((uint32_t)b) << 16;
    return v.f;
}

// ---------- aux: fp32 -> bf16 convert with zero-padding ----------
__global__ void k_conv_pad(const float* __restrict__ in, u16* __restrict__ out,
                           int rIn, int cIn, int cOut, int total8) {
    int idx = blockIdx.x * blockDim.x + threadIdx.x;
    if (idx >= total8) return;
    int c8n = cOut >> 3;
    int r  = idx / c8n;
    int c0 = (idx - r * c8n) << 3;
    u16x8 o;
#pragma unroll
    for (int j = 0; j < 8; ++j) {
        int c = c0 + j;
        o[j] = (r < rIn && c < cIn) ? f2bf(in[(size_t)r * cIn + c]) : (u16)0;
    }
    *(u16x8*)(out + (size_t)r * cOut + c0) = o;
}

// ---------- aux: fp32 [kIn x nIn] -> bf16 transposed [nOut x kOut], zero-padded ----------
__global__ void k_transpose_conv(const float* __restrict__ in, u16* __restrict__ out,
                                 int kIn, int nIn, int kOut) {
    __shared__ float tile[32][33];
    int k0 = blockIdx.x * 32, n0 = blockIdx.y * 32;
    int tx = threadIdx.x, ty = threadIdx.y;   // block (32,8)
#pragma unroll
    for (int i = 0; i < 4; ++i) {
        int k = k0 + ty + i * 8, n = n0 + tx;
        tile[ty + i * 8][tx] = (k < kIn && n < nIn) ? in[(size_t)k * nIn + n] : 0.f;
    }
    __syncthreads();
#pragma unroll
    for (int i = 0; i < 4; ++i) {
        int n = n0 + ty + i * 8, k = k0 + tx;
        out[(size_t)n * kOut + k] = f2bf(tile[tx][ty + i * 8]);
    }
}

// ---------- old 128x128 kernel (kept for G3: N=2048 would give only 128 wgs at 256^2) ----------
template <int MODE>
__global__ __launch_bounds__(256, 4) void k_gemm_bt(
    const u16* __restrict__ A, const u16* __restrict__ B,
    const u16* __restrict__ bias, void* __restrict__ Cv,
    int K, int ldc, int mReal, int nReal) {
    (void)bias;
    __shared__ __align__(16) char lds[32768];
    char* As = lds;
    char* Bs = lds + 16384;

    const int tid  = threadIdx.x;
    const int w    = tid >> 6, lane = tid & 63;
    const int l31  = lane & 31, hi = lane >> 5;
    const int wm   = (w & 1) * 64, wn = (w >> 1) * 64;
    const int bm   = blockIdx.y * 128, bn = blockIdx.x * 128;

    const int srcRow = tid >> 3;
    const int srcCol = (tid & 7) ^ (srcRow & 7);
    const u16* aSrc = A + (size_t)(bm + srcRow) * K + (srcCol << 3);
    const u16* bSrc = B + (size_t)(bn + srcRow) * K + (srcCol << 3);
    char* aDst = As + ((tid & ~63) << 4);
    char* bDst = Bs + ((tid & ~63) << 4);

    const int aRow0 = (wm + l31) * 128;
    const int aRow1 = (wm + 32 + l31) * 128;
    const int bRow0 = (wn + l31) * 128;
    const int bRow1 = (wn + 32 + l31) * 128;

    f32x16 acc[2][2];
#pragma unroll
    for (int i = 0; i < 2; ++i)
#pragma unroll
        for (int j = 0; j < 2; ++j) acc[i][j] = (f32x16)(0.f);

    for (int k0 = 0; k0 < K; k0 += 64) {
#pragma unroll
        for (int t = 0; t < 4; ++t) {
            load_lds16(aSrc + (size_t)(t * 32) * K, aDst + t * 4096);
            load_lds16(bSrc + (size_t)(t * 32) * K, bDst + t * 4096);
        }
        aSrc += 64; bSrc += 64;
        __syncthreads();
#pragma unroll
        for (int ks = 0; ks < 4; ++ks) {
            const int swz = (((ks * 2 + hi) ^ (l31 & 7)) << 4);
            bf16x8 af[2], bfr[2];
            af[0]  = *(const bf16x8*)(As + aRow0 + swz);
            af[1]  = *(const bf16x8*)(As + aRow1 + swz);
            bfr[0] = *(const bf16x8*)(Bs + bRow0 + swz);
            bfr[1] = *(const bf16x8*)(Bs + bRow1 + swz);
#pragma unroll
            for (int mi = 0; mi < 2; ++mi)
#pragma unroll
                for (int ni = 0; ni < 2; ++ni)
                    acc[mi][ni] = __builtin_amdgcn_mfma_f32_32x32x16_bf16(
                        af[mi], bfr[ni], acc[mi][ni], 0, 0, 0);
        }
        __syncthreads();
    }

    float bv[2];
    if (MODE >= 1) {
#pragma unroll
        for (int ni = 0; ni < 2; ++ni) bv[ni] = b2f(bias[bn + wn + ni * 32 + l31]);
    }
#pragma unroll
    for (int mi = 0; mi < 2; ++mi) {
#pragma unroll
        for (int reg = 0; reg < 16; ++reg) {
            int row = bm + wm + mi * 32 + (reg & 3) + 8 * (reg >> 2) + 4 * hi;
#pragma unroll
            for (int ni = 0; ni < 2; ++ni) {
                int col = bn + wn + ni * 32 + l31;
                float v = acc[mi][ni][reg];
                if (MODE == 0) {
                    if (row < mReal && col < nReal)
                        ((u16*)Cv)[(size_t)row * ldc + col] = f2bf(v);
                } else if (MODE == 1) {
                    v += bv[ni];
                    v = v > 0.f ? v : 0.f;
                    ((u16*)Cv)[(size_t)row * ldc + col] = f2bf(v);
                } else {
                    ((float*)Cv)[(size_t)row * ldc + col] = v + bv[ni];
                }
            }
        }
    }
}

// ---------- new: 256x256 8-phase pipelined GEMM (T1+T2+T3+T4+T5) ----------
// 8 waves (2M x 4N), each owns 128x64 as 4x2 of 32x32 MFMA. BK=64, double-buffered
// 128 KiB LDS. Per K-tile: 4 phases split by C-quadrant, every frag ds_read once
// (12/0/8/4 reads). Stage of buf X's next tile issues in the phase AFTER X's last
// ds_read phase (phase-2/6 trailing barrier + per-phase lgkmcnt(0) => all waves'
// reads complete before any stage lands). vmcnt(8) counted waits at phases 3/7
// only: 16 outstanding -> wait leaves the 8 newest in flight (~4-phase lead).
// Raw s_barrier (NOT __syncthreads: that drains vmcnt(0) and kills the pipeline).

#define BARRIER() do { asm volatile("" ::: "memory"); \
                       __builtin_amdgcn_s_barrier(); \
                       asm volatile("" ::: "memory"); } while (0)
#define LGKM0()   do { asm volatile("s_waitcnt lgkmcnt(0)" ::: "memory"); \
                       __builtin_amdgcn_sched_barrier(0); } while (0)
#define VMCNT(n)  asm volatile("s_waitcnt vmcnt(" #n ")" ::: "memory")

// 8 global_load_lds (4 A-sweeps + 4 B-sweeps of 64 rows) for K-tile at elem offset ko
#define STAGE8(bb, ko) do { \
    _Pragma("unroll") for (int t = 0; t < 4; ++t) \
        load_lds16(aS + (ko) + (size_t)(t * 64) * K, (bb) + wOff + t * 8192); \
    _Pragma("unroll") for (int t = 0; t < 4; ++t) \
        load_lds16(bS + (ko) + (size_t)(t * 64) * K, (bb) + 32768 + wOff + t * 8192); \
} while (0)

#define PH_RD_A(bb, mh) do { \
    _Pragma("unroll") for (int m2 = 0; m2 < 2; ++m2) \
    _Pragma("unroll") for (int ks = 0; ks < 4; ++ks) \
        fa[m2][ks] = *(const bf16x8*)((bb) + aRowB + ((mh) * 2 + m2) * 4096 + (chB ^ (ks << 5))); \
} while (0)

#define PH_RD_B(bb, n) do { \
    _Pragma("unroll") for (int ks = 0; ks < 4; ++ks) \
        fb[n][ks] = *(const bf16x8*)((bb) + bRowB + (n) * 4096 + (chB ^ (ks << 5))); \
} while (0)

#define PH_MM(mh, n) do { \
    __builtin_amdgcn_s_setprio(1); \
    _Pragma("unroll") for (int m2 = 0; m2 < 2; ++m2) \
    _Pragma("unroll") for (int ks = 0; ks < 4; ++ks) \
        acc[(mh) * 2 + m2][n] = __builtin_amdgcn_mfma_f32_32x32x16_bf16( \
            fa[m2][ks], fb[n][ks], acc[(mh) * 2 + m2][n], 0, 0, 0); \
    __builtin_amdgcn_s_setprio(0); \
} while (0)

template <int MODE>
__global__ __launch_bounds__(512, 2) void k_gemm256(
    const u16* __restrict__ A, const u16* __restrict__ B,
    const u16* __restrict__ bias, void* __restrict__ Cv,
    int K, int ldc, int mReal, int nReal, int gx) {
    __shared__ __align__(16) char lds[131072];

    const int tid  = threadIdx.x;
    const int w    = tid >> 6, lane = tid & 63;
    const int l31  = lane & 31, hi = lane >> 5;
    const int wr   = w & 1, wc = w >> 1;            // 2 M-waves x 4 N-waves

    // bijective XCD-chunked swizzle (m204 form; nwg=529 is not a multiple of 8)
    const int nwg = (int)gridDim.x;
    const int q   = nwg >> 3, r = nwg & 7;
    const int xcd = (int)blockIdx.x & 7, lid = (int)blockIdx.x >> 3;
    const int wg  = (xcd < r ? xcd * (q + 1) : r * (q + 1) + (xcd - r) * q) + lid;
    const int bm  = (wg / gx) * 256;
    const int bn  = (wg % gx) * 256;

    char* const buf0 = lds;            // A: [256 rows][8 chunks x 16B] swizzled; B at +32768
    char* const buf1 = lds + 65536;

    // staging: pre-swizzled global source, linear LDS dest (rule #21)
    const int srcRow = tid >> 3;                     // 0..63 (+64t per sweep)
    const int srcCh  = (tid & 7) ^ (srcRow & 7);
    const u16* const aS = A + (size_t)(bm + srcRow) * K + (srcCh << 3);
    const u16* const bS = B + (size_t)(bn + srcRow) * K + (srcCh << 3);
    const int wOff = (tid & ~63) << 4;               // wave slot within each 64-row sweep

    // ds_read bases; chunk ks at byte chB ^ (ks<<5)  (chunk^(row&7) swizzle family)
    const int aRowB = (wr * 128 + l31) * 128;
    const int bRowB = 32768 + (wc * 64 + l31) * 128;
    const int chB   = (hi ^ (l31 & 7)) << 4;

    f32x16 acc[4][2];
#pragma unroll
    for (int i = 0; i < 4; ++i)
#pragma unroll
        for (int j = 0; j < 2; ++j) acc[i][j] = (f32x16)(0.f);

    bf16x8 fa[2][4], fb[2][4];

    // prologue: tiles 0,1 in flight; wait tile 0 only (counted)
    STAGE8(buf0, 0);
    STAGE8(buf1, 64);
    VMCNT(8);
    BARRIER();

    const int nIt = K >> 7;          // tile pairs (all K are multiples of 128)
    size_t ko = 128;
#pragma unroll 1
    for (int it = 0; it < nIt; ++it) {
        const bool notLast = (it != nIt - 1);
        // ===== tile 2*it from buf0 : phases 0-3 =====
        PH_RD_A(buf0, 0); PH_RD_B(buf0, 0);                 // 12 reads
        BARRIER(); LGKM0(); PH_MM(0, 0); BARRIER();
        PH_RD_B(buf0, 1);                                   // 4 reads
        BARRIER(); LGKM0(); PH_MM(0, 1); BARRIER();
        PH_RD_A(buf0, 1);                                   // 8 reads (last buf0 reads)
        BARRIER(); LGKM0(); PH_MM(1, 1); BARRIER();
        if (notLast) { STAGE8(buf0, ko); }                  // safe: after ph2 barrier
        BARRIER(); PH_MM(1, 0);                             // uses fa(mh1), fb[0] (regs)
        if (notLast) { VMCNT(8); } else { VMCNT(0); }       // buf1's tile landed
        BARRIER();
        // ===== tile 2*it+1 from buf1 : phases 4-7 =====
        PH_RD_A(buf1, 0); PH_RD_B(buf1, 0);
        BARRIER(); LGKM0(); PH_MM(0, 0); BARRIER();
        PH_RD_B(buf1, 1);
        BARRIER(); LGKM0(); PH_MM(0, 1); BARRIER();
        PH_RD_A(buf1, 1);
        BARRIER(); LGKM0(); PH_MM(1, 1); BARRIER();
        if (notLast) { STAGE8(buf1, ko + 64); ko += 128; }  // safe: after ph6 barrier
        BARRIER(); PH_MM(1, 0);
        if (notLast) { VMCNT(8); }                          // buf0's next tile landed
        BARRIER();
    }

    // epilogue. 32x32 C/D layout: col = lane&31, row = (reg&3) + 8*(reg>>2) + 4*hi
    float bv[2];
    if (MODE >= 1) {
#pragma unroll
        for (int ni = 0; ni < 2; ++ni) bv[ni] = b2f(bias[bn + wc * 64 + ni * 32 + l31]);
    }
#pragma unroll
    for (int mi = 0; mi < 4; ++mi) {
#pragma unroll
        for (int reg = 0; reg < 16; ++reg) {
            const int row = bm + wr * 128 + mi * 32 + (reg & 3) + 8 * (reg >> 2) + 4 * hi;
#pragma unroll
            for (int ni = 0; ni < 2; ++ni) {
                const int col = bn + wc * 64 + ni * 32 + l31;
                float v = acc[mi][ni][reg];
                if (MODE == 0) {
                    if (row < mReal && col < nReal)
                        ((u16*)Cv)[(size_t)row * ldc + col] = f2bf(v);
                } else if (MODE == 1) {
                    v += bv[ni];
                    v = v > 0.f ? v : 0.f;
                    ((u16*)Cv)[(size_t)row * ldc + col] = f2bf(v);
                } else {
                    ((float*)Cv)[(size_t)row * ldc + col] = v + bv[ni];
                }
            }
        }
    }
}

// ---------- launch ----------
// Sizes: D_IN=2048, D_H=4096, D_OUT=2048, B=4096; SIZE_N=5794, SIZE_M=2897
// Padded GEMM0 dims: M=N=5888 (23*256), K=2944 (23*128)
// Vf flat unpack offsets (elems):
//   W1 @ 0, b1 @ 8388608, W2 @ 8392704, b2 @ 25169920, W3 @ 25174016, b3 @ 33562624
extern "C" void kernel_launch(void* const* d_in, const int* in_sizes, int n_in,
                              void* d_out, int out_size, void* d_ws, size_t ws_size,
                              hipStream_t stream) {
    (void)in_sizes; (void)n_in; (void)out_size; (void)ws_size;
    const float* x  = (const float*)d_in[0];
    const float* V1 = (const float*)d_in[1];
    const float* V2 = (const float*)d_in[2];

    char* ws = (char*)d_ws;
    u16* Vf   = (u16*)(ws);                            // 5794*5794 bf16 -> 67,140,872 B
    u16* V1b  = (u16*)(ws + 67141120);                 // [5888 x 2944] bf16 = 34,668,544 B
    u16* V2bT = (u16*)(ws + 67141120 + 34668544);      // [5888 x 2944] bf16
    u16* Xb   = (u16*)(ws + 67141120 + 2 * 34668544);  // [4096 x 2048] bf16
    u16* H1   = V1b;   // dead after GEMM0
    u16* H2   = V2bT;

    k_conv_pad<<<8464, 256, 0, stream>>>(V1, V1b, 5794, 2897, 2944, 5888 * 2944 / 8);
    k_transpose_conv<<<dim3(92, 184), dim3(32, 8), 0, stream>>>(V2, V2bT, 2897, 5794, 2944);
    k_conv_pad<<<4096, 256, 0, stream>>>(x, Xb, 4096, 2048, 2048, 4096 * 2048 / 8);

    // G0: Vf = V1 @ V2  (padded 5888x5888x2944, guarded store into flat [5794x5794])
    k_gemm256<0><<<529, 512, 0, stream>>>(V1b, V2bT, nullptr, Vf,
                                          2944, 5794, 5794, 5794, 23);
    // G1: H1 = relu(Xb @ W1^T + b1)   [4096x4096], K=2048
    k_gemm256<1><<<256, 512, 0, stream>>>(Xb, Vf + 0, Vf + 8388608, H1,
                                          2048, 4096, 4096, 4096, 16);
    // G2: H2 = relu(H1 @ W2^T + b2)   [4096x4096], K=4096
    k_gemm256<1><<<256, 512, 0, stream>>>(H1, Vf + 8392704, Vf + 25169920, H2,
                                          4096, 4096, 4096, 4096, 16);
    // G3: out = H2 @ W3^T + b3        [4096x2048] fp32, K=4096 (128^2 kernel: 512 wgs)
    k_gemm_bt<2><<<dim3(16, 32), 256, 0, stream>>>(H2, Vf + 25174016, Vf + 33562624, d_out,
                                                   4096, 2048, 4096, 2048);
}

// Round 2
// 764.747 us; speedup vs baseline: 1.0399x; 1.0337x over previous
//
#include <hip/hip_runtime.h>
#include <stdint.h>

// ---------- types ----------
typedef __attribute__((ext_vector_type(8)))  __bf16 bf16x8;   // MFMA A/B frag (4 VGPRs)
typedef __attribute__((ext_vector_type(16))) float  f32x16;   // 32x32 MFMA C/D frag
typedef unsigned short u16;
typedef __attribute__((ext_vector_type(8))) unsigned short u16x8;

#define GLOBAL_AS __attribute__((address_space(1)))
#define LDS_AS    __attribute__((address_space(3)))

__device__ __forceinline__ void load_lds16(const void* g, void* l) {
    __builtin_amdgcn_global_load_lds((const GLOBAL_AS void*)g, (LDS_AS void*)l, 16, 0, 0);
}

__device__ __forceinline__ u16 f2bf(float f) {
    union { float f; uint32_t u; } v; v.f = f;
    uint32_t r = v.u + 0x7FFFu + ((v.u >> 16) & 1u);   // RNE
    return (u16)(r >> 16);
}
__device__ __forceinline__ float b2f(u16 b) {
    union { uint32_t u; float f; } v; v.u = ((uint32_t)b) << 16;
    return v.f;
}

// ---------- aux: fp32 -> bf16 convert with zero-padding ----------
__global__ void k_conv_pad(const float* __restrict__ in, u16* __restrict__ out,
                           int rIn, int cIn, int cOut, int total8) {
    int idx = blockIdx.x * blockDim.x + threadIdx.x;
    if (idx >= total8) return;
    int c8n = cOut >> 3;
    int r  = idx / c8n;
    int c0 = (idx - r * c8n) << 3;
    u16x8 o;
#pragma unroll
    for (int j = 0; j < 8; ++j) {
        int c = c0 + j;
        o[j] = (r < rIn && c < cIn) ? f2bf(in[(size_t)r * cIn + c]) : (u16)0;
    }
    *(u16x8*)(out + (size_t)r * cOut + c0) = o;
}

// ---------- aux: fp32 [kIn x nIn] -> bf16 transposed [nOut x kOut], zero-padded ----------
__global__ void k_transpose_conv(const float* __restrict__ in, u16* __restrict__ out,
                                 int kIn, int nIn, int kOut) {
    __shared__ float tile[32][33];
    int k0 = blockIdx.x * 32, n0 = blockIdx.y * 32;
    int tx = threadIdx.x, ty = threadIdx.y;   // block (32,8)
#pragma unroll
    for (int i = 0; i < 4; ++i) {
        int k = k0 + ty + i * 8, n = n0 + tx;
        tile[ty + i * 8][tx] = (k < kIn && n < nIn) ? in[(size_t)k * nIn + n] : 0.f;
    }
    __syncthreads();
#pragma unroll
    for (int i = 0; i < 4; ++i) {
        int n = n0 + ty + i * 8, k = k0 + tx;
        out[(size_t)n * kOut + k] = f2bf(tile[tx][ty + i * 8]);
    }
}

// ---------- old 128x128 kernel (kept for G3: N=2048 gives only 128 wgs at 256^2) ----------
template <int MODE>
__global__ __launch_bounds__(256, 4) void k_gemm_bt(
    const u16* __restrict__ A, const u16* __restrict__ B,
    const u16* __restrict__ bias, void* __restrict__ Cv,
    int K, int ldc, int mReal, int nReal) {
    (void)bias;
    __shared__ __align__(16) char lds[32768];
    char* As = lds;
    char* Bs = lds + 16384;

    const int tid  = threadIdx.x;
    const int w    = tid >> 6, lane = tid & 63;
    const int l31  = lane & 31, hi = lane >> 5;
    const int wm   = (w & 1) * 64, wn = (w >> 1) * 64;
    const int bm   = blockIdx.y * 128, bn = blockIdx.x * 128;

    const int srcRow = tid >> 3;
    const int srcCol = (tid & 7) ^ (srcRow & 7);
    const u16* aSrc = A + (size_t)(bm + srcRow) * K + (srcCol << 3);
    const u16* bSrc = B + (size_t)(bn + srcRow) * K + (srcCol << 3);
    char* aDst = As + ((tid & ~63) << 4);
    char* bDst = Bs + ((tid & ~63) << 4);

    const int aRow0 = (wm + l31) * 128;
    const int aRow1 = (wm + 32 + l31) * 128;
    const int bRow0 = (wn + l31) * 128;
    const int bRow1 = (wn + 32 + l31) * 128;

    f32x16 acc[2][2];
#pragma unroll
    for (int i = 0; i < 2; ++i)
#pragma unroll
        for (int j = 0; j < 2; ++j) acc[i][j] = (f32x16)(0.f);

    for (int k0 = 0; k0 < K; k0 += 64) {
#pragma unroll
        for (int t = 0; t < 4; ++t) {
            load_lds16(aSrc + (size_t)(t * 32) * K, aDst + t * 4096);
            load_lds16(bSrc + (size_t)(t * 32) * K, bDst + t * 4096);
        }
        aSrc += 64; bSrc += 64;
        __syncthreads();
#pragma unroll
        for (int ks = 0; ks < 4; ++ks) {
            const int swz = (((ks * 2 + hi) ^ (l31 & 7)) << 4);
            bf16x8 af[2], bfr[2];
            af[0]  = *(const bf16x8*)(As + aRow0 + swz);
            af[1]  = *(const bf16x8*)(As + aRow1 + swz);
            bfr[0] = *(const bf16x8*)(Bs + bRow0 + swz);
            bfr[1] = *(const bf16x8*)(Bs + bRow1 + swz);
#pragma unroll
            for (int mi = 0; mi < 2; ++mi)
#pragma unroll
                for (int ni = 0; ni < 2; ++ni)
                    acc[mi][ni] = __builtin_amdgcn_mfma_f32_32x32x16_bf16(
                        af[mi], bfr[ni], acc[mi][ni], 0, 0, 0);
        }
        __syncthreads();
    }

    float bv[2];
    if (MODE >= 1) {
#pragma unroll
        for (int ni = 0; ni < 2; ++ni) bv[ni] = b2f(bias[bn + wn + ni * 32 + l31]);
    }
#pragma unroll
    for (int mi = 0; mi < 2; ++mi) {
#pragma unroll
        for (int reg = 0; reg < 16; ++reg) {
            int row = bm + wm + mi * 32 + (reg & 3) + 8 * (reg >> 2) + 4 * hi;
#pragma unroll
            for (int ni = 0; ni < 2; ++ni) {
                int col = bn + wn + ni * 32 + l31;
                float v = acc[mi][ni][reg];
                if (MODE == 0) {
                    if (row < mReal && col < nReal)
                        ((u16*)Cv)[(size_t)row * ldc + col] = f2bf(v);
                } else if (MODE == 1) {
                    v += bv[ni];
                    v = v > 0.f ? v : 0.f;
                    ((u16*)Cv)[(size_t)row * ldc + col] = f2bf(v);
                } else {
                    ((float*)Cv)[(size_t)row * ldc + col] = v + bv[ni];
                }
            }
        }
    }
}

// ---------- 256x256 pipelined GEMM v2: ks-major phases, 2 barriers/iter, persistent tiles ----
// 8 waves (2M x 4N), each owns 128x64. BK=64, double-buffered 128 KiB LDS.
// Per K-tile: 4 ks-major phases, each {6 ds_read_b128; lgkmcnt(0); 8 MFMA} — balanced
// LDS (48KB/phase/CU ~ 192cy) vs MFMA (128cy/SIMD/phase). Only 2 barriers per 2-tile
// iteration, each preceded by per-wave lgkmcnt(0)+vmcnt(0):
//   B_B (ph3): all waves drained buf0 reads + confirmed buf1 stage landed
//              -> restage buf0 (next even tile) after it, read buf1 after it.
//   B_A (ph7): all waves drained buf1 reads + confirmed buf0 stage landed
//              -> restage buf1 (loop top) after it, read buf0 after it.
// vmcnt lead = 4 phases (~800+cy). Persistent v-loop kills the grid-round tail
// (529 tiles / 512 blocks: blocks w/ swizzled id<17 run 2 tiles, start in round 1
// -> makespan 2 rounds, not 3).

#define BARRIER() do { asm volatile("" ::: "memory"); \
                       __builtin_amdgcn_s_barrier(); \
                       asm volatile("" ::: "memory"); } while (0)
#define LGKM0()   do { asm volatile("s_waitcnt lgkmcnt(0)" ::: "memory"); \
                       __builtin_amdgcn_sched_barrier(0); } while (0)
#define VMCNT0()  do { asm volatile("s_waitcnt vmcnt(0)" ::: "memory"); \
                       __builtin_amdgcn_sched_barrier(0); } while (0)

// 8 global_load_lds (4 A-sweeps + 4 B-sweeps of 64 rows) for K-tile at elem offset ko
#define STAGE8(bb, koff) do { \
    _Pragma("unroll") for (int t = 0; t < 4; ++t) \
        load_lds16(aS + (koff) + (size_t)(t * 64) * K, (bb) + wOff + t * 8192); \
    _Pragma("unroll") for (int t = 0; t < 4; ++t) \
        load_lds16(bS + (koff) + (size_t)(t * 64) * K, (bb) + 32768 + wOff + t * 8192); \
} while (0)

// one ks-major phase: 6 reads (4 A m-blocks + 2 B n-blocks at k-slice p), MID hook,
// lgkm drain, 8 MFMA (8 independent acc chains)
#define PH(bb, p, MID) do { \
    const int co_ = chB ^ ((p) << 5); \
    bf16x8 fa0_ = *(const bf16x8*)((bb) + aRowB +     0 + co_); \
    bf16x8 fa1_ = *(const bf16x8*)((bb) + aRowB +  4096 + co_); \
    bf16x8 fa2_ = *(const bf16x8*)((bb) + aRowB +  8192 + co_); \
    bf16x8 fa3_ = *(const bf16x8*)((bb) + aRowB + 12288 + co_); \
    bf16x8 fb0_ = *(const bf16x8*)((bb) + bRowB +     0 + co_); \
    bf16x8 fb1_ = *(const bf16x8*)((bb) + bRowB +  4096 + co_); \
    MID \
    LGKM0(); \
    __builtin_amdgcn_s_setprio(1); \
    acc[0][0] = __builtin_amdgcn_mfma_f32_32x32x16_bf16(fa0_, fb0_, acc[0][0], 0, 0, 0); \
    acc[1][0] = __builtin_amdgcn_mfma_f32_32x32x16_bf16(fa1_, fb0_, acc[1][0], 0, 0, 0); \
    acc[2][0] = __builtin_amdgcn_mfma_f32_32x32x16_bf16(fa2_, fb0_, acc[2][0], 0, 0, 0); \
    acc[3][0] = __builtin_amdgcn_mfma_f32_32x32x16_bf16(fa3_, fb0_, acc[3][0], 0, 0, 0); \
    acc[0][1] = __builtin_amdgcn_mfma_f32_32x32x16_bf16(fa0_, fb1_, acc[0][1], 0, 0, 0); \
    acc[1][1] = __builtin_amdgcn_mfma_f32_32x32x16_bf16(fa1_, fb1_, acc[1][1], 0, 0, 0); \
    acc[2][1] = __builtin_amdgcn_mfma_f32_32x32x16_bf16(fa2_, fb1_, acc[2][1], 0, 0, 0); \
    acc[3][1] = __builtin_amdgcn_mfma_f32_32x32x16_bf16(fa3_, fb1_, acc[3][1], 0, 0, 0); \
    __builtin_amdgcn_s_setprio(0); \
} while (0)

#define PH_PLAIN ;
#define PH_SYNC  LGKM0(); VMCNT0(); BARRIER();

template <int MODE>
__global__ __launch_bounds__(512, 2) void k_gemm256(
    const u16* __restrict__ A, const u16* __restrict__ B,
    const u16* __restrict__ bias, void* __restrict__ Cv,
    int K, int ldc, int mReal, int nReal, int gx, int nTiles) {
    __shared__ __align__(16) char lds[131072];

    const int tid  = threadIdx.x;
    const int w    = tid >> 6, lane = tid & 63;
    const int l31  = lane & 31, hi = lane >> 5;
    const int wr   = w & 1, wc = w >> 1;            // 2 M-waves x 4 N-waves

    // XCD-chunked swizzle (grid divisible by 8): contiguous tile chunk per XCD
    const int cpx = (int)gridDim.x >> 3;
    const int wg0 = ((int)blockIdx.x & 7) * cpx + ((int)blockIdx.x >> 3);

    char* const buf0 = lds;            // A: [256 rows][8 chunks x 16B] swizzled; B at +32768
    char* const buf1 = lds + 65536;

    // staging geometry: pre-swizzled global source, linear LDS dest (rule #21)
    const int srcRow = tid >> 3;                     // 0..63 (+64t per sweep)
    const int srcCh  = (tid & 7) ^ (srcRow & 7);
    const int wOff   = (tid & ~63) << 4;             // wave slot within each 64-row sweep

    // ds_read bases; k-slice p chunk at byte chB ^ (p<<5)  (chunk^(row&7) swizzle)
    const int aRowB = (wr * 128 + l31) * 128;
    const int bRowB = 32768 + (wc * 64 + l31) * 128;
    const int chB   = (hi ^ (l31 & 7)) << 4;

    const int nIt = K >> 7;            // K-tile pairs (all K multiples of 128)

    for (int v = wg0; v < nTiles; v += (int)gridDim.x) {
        const int bm = (v / gx) * 256;
        const int bn = (v % gx) * 256;
        const u16* const aS = A + (size_t)(bm + srcRow) * K + (srcCh << 3);
        const u16* const bS = B + (size_t)(bn + srcRow) * K + (srcCh << 3);

        f32x16 acc[4][2];
#pragma unroll
        for (int i = 0; i < 4; ++i)
#pragma unroll
            for (int j = 0; j < 2; ++j) acc[i][j] = (f32x16)(0.f);

        // prologue: tile 0 -> buf0
        STAGE8(buf0, 0);
        VMCNT0();
        BARRIER();

        size_t ko = 0;
#pragma unroll 1
        for (int it = 0; it < nIt; ++it) {
            STAGE8(buf1, ko + 64);                   // odd tile of this iter (after B_A)
            PH(buf0, 0, PH_PLAIN);
            PH(buf0, 1, PH_PLAIN);
            PH(buf0, 2, PH_PLAIN);
            // ph3: drain buf0 reads, confirm buf1 landed, B_B, restage buf0
            PH(buf0, 3, PH_SYNC if (it + 1 < nIt) { STAGE8(buf0, ko + 128); });
            PH(buf1, 0, PH_PLAIN);
            PH(buf1, 1, PH_PLAIN);
            PH(buf1, 2, PH_PLAIN);
            // ph7: drain buf1 reads, confirm buf0 landed, B_A
            PH(buf1, 3, PH_SYNC);
            ko += 128;
        }

        // epilogue. 32x32 C/D layout: col = lane&31, row = (reg&3) + 8*(reg>>2) + 4*hi
        float bv[2];
        if (MODE >= 1) {
#pragma unroll
            for (int ni = 0; ni < 2; ++ni) bv[ni] = b2f(bias[bn + wc * 64 + ni * 32 + l31]);
        }
#pragma unroll
        for (int mi = 0; mi < 4; ++mi) {
#pragma unroll
            for (int reg = 0; reg < 16; ++reg) {
                const int row = bm + wr * 128 + mi * 32 + (reg & 3) + 8 * (reg >> 2) + 4 * hi;
#pragma unroll
                for (int ni = 0; ni < 2; ++ni) {
                    const int col = bn + wc * 64 + ni * 32 + l31;
                    float vv = acc[mi][ni][reg];
                    if (MODE == 0) {
                        if (row < mReal && col < nReal)
                            ((u16*)Cv)[(size_t)row * ldc + col] = f2bf(vv);
                    } else if (MODE == 1) {
                        vv += bv[ni];
                        vv = vv > 0.f ? vv : 0.f;
                        ((u16*)Cv)[(size_t)row * ldc + col] = f2bf(vv);
                    } else {
                        ((float*)Cv)[(size_t)row * ldc + col] = vv + bv[ni];
                    }
                }
            }
        }
    }
}

// ---------- launch ----------
// Sizes: D_IN=2048, D_H=4096, D_OUT=2048, B=4096; SIZE_N=5794, SIZE_M=2897
// Padded GEMM0 dims: M=N=5888 (23*256), K=2944 (23*128)
// Vf flat unpack offsets (elems):
//   W1 @ 0, b1 @ 8388608, W2 @ 8392704, b2 @ 25169920, W3 @ 25174016, b3 @ 33562624
extern "C" void kernel_launch(void* const* d_in, const int* in_sizes, int n_in,
                              void* d_out, int out_size, void* d_ws, size_t ws_size,
                              hipStream_t stream) {
    (void)in_sizes; (void)n_in; (void)out_size; (void)ws_size;
    const float* x  = (const float*)d_in[0];
    const float* V1 = (const float*)d_in[1];
    const float* V2 = (const float*)d_in[2];

    char* ws = (char*)d_ws;
    u16* Vf   = (u16*)(ws);                            // 5794*5794 bf16 -> 67,140,872 B
    u16* V1b  = (u16*)(ws + 67141120);                 // [5888 x 2944] bf16 = 34,668,544 B
    u16* V2bT = (u16*)(ws + 67141120 + 34668544);      // [5888 x 2944] bf16
    u16* Xb   = (u16*)(ws + 67141120 + 2 * 34668544);  // [4096 x 2048] bf16
    u16* H1   = V1b;   // dead after GEMM0
    u16* H2   = V2bT;

    k_conv_pad<<<8464, 256, 0, stream>>>(V1, V1b, 5794, 2897, 2944, 5888 * 2944 / 8);
    k_transpose_conv<<<dim3(92, 184), dim3(32, 8), 0, stream>>>(V2, V2bT, 2897, 5794, 2944);
    k_conv_pad<<<4096, 256, 0, stream>>>(x, Xb, 4096, 2048, 2048, 4096 * 2048 / 8);

    // G0: Vf = V1 @ V2  (padded 5888x5888x2944; 529 tiles over 512 blocks -> 2 rounds)
    k_gemm256<0><<<512, 512, 0, stream>>>(V1b, V2bT, nullptr, Vf,
                                          2944, 5794, 5794, 5794, 23, 529);
    // G1: H1 = relu(Xb @ W1^T + b1)   [4096x4096], K=2048 (256 tiles, exact 1 round)
    k_gemm256<1><<<256, 512, 0, stream>>>(Xb, Vf + 0, Vf + 8388608, H1,
                                          2048, 4096, 4096, 4096, 16, 256);
    // G2: H2 = relu(H1 @ W2^T + b2)   [4096x4096], K=4096
    k_gemm256<1><<<256, 512, 0, stream>>>(H1, Vf + 8392704, Vf + 25169920, H2,
                                          4096, 4096, 4096, 4096, 16, 256);
    // G3: out = H2 @ W3^T + b3        [4096x2048] fp32, K=4096 (128^2 kernel: 512 wgs)
    k_gemm_bt<2><<<dim3(16, 32), 256, 0, stream>>>(H2, Vf + 25174016, Vf + 33562624, d_out,
                                                   4096, 2048, 4096, 2048);
}